// Round 1
// baseline (714.796 us; speedup 1.0000x reference)
//
#include <hip/hip_runtime.h>

// Problem dims (fixed by reference)
#define S_DIM 2048
#define B_DIM 32
#define H_DIM 1024
#define ROWS  (S_DIM * B_DIM)   // 65536 GEMM rows, row = s*32 + b

typedef __attribute__((ext_vector_type(8))) short s16x8;  // 8 bf16 (4 VGPRs) MFMA operand
typedef __attribute__((ext_vector_type(4))) float f32x4;  // MFMA accumulator

// ---- helpers ----------------------------------------------------------------

// Pack two fp32 -> one u32 holding [bf16(a) | bf16(b)<<16], round-to-nearest
// (half-up: +0x8000 then truncate; one v_add each + one v_perm_b32).
__device__ __forceinline__ unsigned pack2_bf16(float a, float b) {
  unsigned ua = __float_as_uint(a) + 0x8000u;
  unsigned ub = __float_as_uint(b) + 0x8000u;
  // v_perm_b32: src0 supplies bytes 4-7 of the concat, src1 bytes 0-3.
  // sel 0x07060302 -> [ua.b2, ua.b3, ub.b2, ub.b3] = low16(bf16 a), high16(bf16 b)
  return __builtin_amdgcn_perm(ub, ua, 0x07060302u);
}

__device__ __forceinline__ unsigned short bf16_rne(float f) {
  unsigned u = __float_as_uint(f);
  return (unsigned short)((u + 0x7FFFu + ((u >> 16) & 1u)) >> 16);
}

// tanh via one v_exp_f32; clamp keeps exp finite (tanh saturated long before 15)
__device__ __forceinline__ float fast_tanh(float x) {
  x = fminf(15.0f, fmaxf(-15.0f, x));
  float z = __expf(-2.0f * x);
  return (1.0f - z) * __builtin_amdgcn_rcpf(1.0f + z);
}

// async global->LDS, 16B per lane. LDS dest must equal wave-uniform base + lane*16.
__device__ __forceinline__ void load_lds16(const void* g, void* l) {
  __builtin_amdgcn_global_load_lds(
      (const __attribute__((address_space(1))) unsigned int*)g,
      (__attribute__((address_space(3))) unsigned int*)l, 16, 0, 0);
}

// ---- K1: hid_proj[b][h] = hidden[b,:] . attn_w[h, 0:1024] + attn_b[h] (fp32) -
__global__ void hidproj_kernel(const float* __restrict__ hidden,
                               const float* __restrict__ attn_w,
                               const float* __restrict__ attn_b,
                               float* __restrict__ hp) {
  int b  = blockIdx.y;
  int hl = threadIdx.x & 63;
  int h  = blockIdx.x * 64 + hl;
  int kp = threadIdx.x >> 6;  // 4-way k-split for latency hiding
  const f32x4* wrow = (const f32x4*)(attn_w + (size_t)h * (2 * H_DIM)) + kp * 64;
  const f32x4* xrow = (const f32x4*)(hidden + (size_t)b * H_DIM) + kp * 64;
  float s = 0.f;
#pragma unroll 8
  for (int k = 0; k < 64; ++k) {
    f32x4 w = wrow[k], x = xrow[k];
    s = fmaf(w.x, x.x, s); s = fmaf(w.y, x.y, s);
    s = fmaf(w.z, x.z, s); s = fmaf(w.w, x.w, s);
  }
  __shared__ float red[4][64];
  red[kp][hl] = s;
  __syncthreads();
  if (kp == 0) {
    float t = red[0][hl] + red[1][hl] + red[2][hl] + red[3][hl] + attn_b[h];
    hp[(size_t)b * H_DIM + h] = t;
  }
}

// ---- K2: pack W2 = attn_w[:, H:2H] to bf16, layout [h][k] (== MFMA B layout) -
__global__ void packW2_kernel(const float* __restrict__ attn_w,
                              unsigned short* __restrict__ Bp) {
  int idx = blockIdx.x * 256 + threadIdx.x;   // 262144 threads, 4 elems each
  int h  = idx >> 8;
  int kc = idx & 255;
  f32x4 w = *(const f32x4*)(attn_w + (size_t)h * (2 * H_DIM) + H_DIM + kc * 4);
  ushort4 o;
  o.x = bf16_rne(w.x); o.y = bf16_rne(w.y); o.z = bf16_rne(w.z); o.w = bf16_rne(w.w);
  *(ushort4*)(Bp + (size_t)h * H_DIM + kc * 4) = o;
}

// ---- K3: fused GEMM(enc x W2^T) + tanh + dot-v -> scores (atomic partials) ---
// Tile 128 rows x 256 cols, BK=32, 4 waves in 2x2, each wave 64x128 via 4x8
// frags of v_mfma_f32_16x16x32_bf16.
__global__ __launch_bounds__(256, 2)
void gemm_scores_kernel(const float* __restrict__ enc,
                        const unsigned short* __restrict__ Bp,
                        const float* __restrict__ hp,
                        const float* __restrict__ v,
                        float* __restrict__ scores) {
  // A staged chunk-transposed: As[kc][row][4 floats]; flat 16B-chunk index
  // q = kc*128+row matches lane-contiguous DMA AND gives conflict-free
  // ds_read_b128 fragment reads (bank = (row*4+j)&31 covers all banks).
  __shared__ __align__(16) float As[8][128][4];           // 16 KiB
  __shared__ __align__(16) unsigned short Bs[256][32];    // 16 KiB, [n][k]
  const int tid  = threadIdx.x;
  const int lane = tid & 63;
  const int wid  = tid >> 6;
  const int wm   = wid >> 1;       // wave row-half (0..1)
  const int wn   = wid & 1;        // wave col-half (0..1)
  const int m16  = lane & 15;
  const int quad = lane >> 4;
  const int row0 = blockIdx.y * 128;
  const int n0   = blockIdx.x * 256;

  f32x4 acc[4][8];
#pragma unroll
  for (int i = 0; i < 4; ++i)
#pragma unroll
    for (int j = 0; j < 8; ++j) acc[i][j] = (f32x4){0.f, 0.f, 0.f, 0.f};

  for (int k0 = 0; k0 < H_DIM; k0 += 32) {
#pragma unroll
    for (int c = 0; c < 4; ++c) {
      int q  = c * 256 + tid;
      int r  = q & 127;                 // A: chunk q -> (row r, k-chunk kc)
      int kc = q >> 7;
      load_lds16(enc + (size_t)(row0 + r) * H_DIM + k0 + kc * 4, &As[kc][r][0]);
      int n  = q >> 2;                  // B: chunk q -> (n, k-chunk kb)
      int kb = q & 3;
      load_lds16(Bp + (size_t)(n0 + n) * H_DIM + k0 + kb * 8, &Bs[n][kb * 8]);
    }
    __syncthreads();

    s16x8 af[4], bf[8];
#pragma unroll
    for (int mf = 0; mf < 4; ++mf) {
      int r = wm * 64 + mf * 16 + m16;
      f32x4 a0 = *(const f32x4*)&As[quad * 2][r][0];      // k = quad*8+0..3
      f32x4 a1 = *(const f32x4*)&As[quad * 2 + 1][r][0];  // k = quad*8+4..7
      union { s16x8 v8; unsigned u[4]; } pk;
      pk.u[0] = pack2_bf16(a0.x, a0.y);
      pk.u[1] = pack2_bf16(a0.z, a0.w);
      pk.u[2] = pack2_bf16(a1.x, a1.y);
      pk.u[3] = pack2_bf16(a1.z, a1.w);
      af[mf] = pk.v8;
    }
#pragma unroll
    for (int nf = 0; nf < 8; ++nf) {
      int n = wn * 128 + nf * 16 + m16;
      bf[nf] = *(const s16x8*)&Bs[n][quad * 8];           // k = quad*8+0..7
    }
#pragma unroll
    for (int mf = 0; mf < 4; ++mf)
#pragma unroll
      for (int nf = 0; nf < 8; ++nf)
        acc[mf][nf] = __builtin_amdgcn_mfma_f32_16x16x32_bf16(
            af[mf], bf[nf], acc[mf][nf], 0, 0, 0);
    __syncthreads();
  }

  // Epilogue: energy = tanh(acc + hid_proj + (bias folded into hid_proj)),
  // partial score = sum over this block's 128 cols of energy*v, one atomic
  // per (row, wave-col-half). C/D layout: col = lane&15, row = quad*4+reg.
#pragma unroll
  for (int mf = 0; mf < 4; ++mf) {
#pragma unroll
    for (int reg = 0; reg < 4; ++reg) {
      int rl    = wm * 64 + mf * 16 + quad * 4 + reg;
      int row_g = row0 + rl;
      int b     = row_g & 31;     // row = s*32 + b
      int s     = row_g >> 5;
      float psum = 0.f;
#pragma unroll
      for (int nf = 0; nf < 8; ++nf) {
        int col = n0 + wn * 128 + nf * 16 + m16;
        float e = acc[mf][nf][reg] + hp[b * H_DIM + col];
        e = fast_tanh(e);
        psum = fmaf(e, v[col], psum);
      }
      psum += __shfl_xor(psum, 1);
      psum += __shfl_xor(psum, 2);
      psum += __shfl_xor(psum, 4);
      psum += __shfl_xor(psum, 8);
      if (m16 == 0) atomicAdd(&scores[b * S_DIM + s], psum);
    }
  }
}

// ---- K4: masked softmax over s per batch row -> attention weights ------------
__global__ void softmax_kernel(const float* __restrict__ scores,
                               const int* __restrict__ lens,
                               float* __restrict__ wout) {
  int b = blockIdx.x, tid = threadIdx.x;
  int len = lens[b];
  float vals[8];
  float m = -3.0e38f;
#pragma unroll
  for (int i = 0; i < 8; ++i) {
    int s = i * 256 + tid;
    float x = scores[b * S_DIM + s];
    vals[i] = (s < len) ? x : -3.0e38f;
    m = fmaxf(m, vals[i]);
  }
#pragma unroll
  for (int off = 32; off > 0; off >>= 1) m = fmaxf(m, __shfl_xor(m, off));
  __shared__ float redm[4], reds[4];
  int wid = tid >> 6, lane = tid & 63;
  if (lane == 0) redm[wid] = m;
  __syncthreads();
  m = fmaxf(fmaxf(redm[0], redm[1]), fmaxf(redm[2], redm[3]));

  float e[8];
  float sum = 0.f;
#pragma unroll
  for (int i = 0; i < 8; ++i) {
    int s = i * 256 + tid;
    e[i] = (s < len) ? __expf(vals[i] - m) : 0.f;  // masked -> exactly 0 (matches ref underflow)
    sum += e[i];
  }
#pragma unroll
  for (int off = 32; off > 0; off >>= 1) sum += __shfl_xor(sum, off);
  if (lane == 0) reds[wid] = sum;
  __syncthreads();
  sum = reds[0] + reds[1] + reds[2] + reds[3];
  float inv = 1.0f / sum;
#pragma unroll
  for (int i = 0; i < 8; ++i)
    wout[b * S_DIM + i * 256 + tid] = e[i] * inv;
}

// ---- K5: context[b][h] = sum_s w[b][s] * enc[s][b][h] ------------------------
__global__ void context_kernel(const float* __restrict__ enc,
                               const float* __restrict__ wts,
                               float* __restrict__ ctx) {
  int sc = blockIdx.x;            // 32 chunks of 64 s
  int b  = blockIdx.y;
  int tid = threadIdx.x;          // 256 threads x float4 = 1024 h
  f32x4 acc = (f32x4){0.f, 0.f, 0.f, 0.f};
  const float* wrow = wts + (size_t)b * S_DIM + sc * 64;
  for (int i = 0; i < 64; ++i) {
    float w = wrow[i];            // wave-uniform value -> uniform branch
    if (w != 0.0f) {
      f32x4 ev = *(const f32x4*)(enc + ((size_t)(sc * 64 + i) * B_DIM + b) * H_DIM + tid * 4);
      acc.x = fmaf(w, ev.x, acc.x);
      acc.y = fmaf(w, ev.y, acc.y);
      acc.z = fmaf(w, ev.z, acc.z);
      acc.w = fmaf(w, ev.w, acc.w);
    }
  }
  float* dst = ctx + (size_t)b * H_DIM + tid * 4;
  atomicAdd(dst + 0, acc.x);
  atomicAdd(dst + 1, acc.y);
  atomicAdd(dst + 2, acc.z);
  atomicAdd(dst + 3, acc.w);
}

// ---- launch -----------------------------------------------------------------
extern "C" void kernel_launch(void* const* d_in, const int* in_sizes, int n_in,
                              void* d_out, int out_size, void* d_ws, size_t ws_size,
                              hipStream_t stream) {
  const float* hidden = (const float*)d_in[0];   // (B,H)
  const float* enc    = (const float*)d_in[1];   // (S,B,H)
  const int*   lens   = (const int*)d_in[2];     // (B,)
  const float* attn_w = (const float*)d_in[3];   // (H,2H)
  const float* attn_b = (const float*)d_in[4];   // (H,)
  const float* v      = (const float*)d_in[5];   // (H,)

  float* out_ctx = (float*)d_out;                      // B*H context
  float* out_w   = (float*)d_out + B_DIM * H_DIM;      // B*S weights

  // ws layout: scores (B*S f32) | hid_proj (B*H f32) | W2 bf16 (H*H u16) ~ 2.5 MB
  float* scores = (float*)d_ws;
  float* hp     = scores + B_DIM * S_DIM;
  unsigned short* Bp = (unsigned short*)(hp + B_DIM * H_DIM);

  hipMemsetAsync(scores, 0, (size_t)B_DIM * S_DIM * sizeof(float), stream);
  hipMemsetAsync(out_ctx, 0, (size_t)B_DIM * H_DIM * sizeof(float), stream);

  hipLaunchKernelGGL(hidproj_kernel, dim3(H_DIM / 64, B_DIM), dim3(256), 0, stream,
                     hidden, attn_w, attn_b, hp);
  hipLaunchKernelGGL(packW2_kernel, dim3((H_DIM * H_DIM / 4) / 256), dim3(256), 0, stream,
                     attn_w, Bp);
  hipLaunchKernelGGL(gemm_scores_kernel, dim3(H_DIM / 256, ROWS / 128), dim3(256), 0, stream,
                     enc, Bp, hp, v, scores);
  hipLaunchKernelGGL(softmax_kernel, dim3(B_DIM), dim3(256), 0, stream,
                     scores, lens, out_w);
  hipLaunchKernelGGL(context_kernel, dim3(S_DIM / 64, B_DIM), dim3(256), 0, stream,
                     enc, out_w, out_ctx);
}